// Round 1
// baseline (38.084 us; speedup 1.0000x reference)
//
#include <hip/hip_runtime.h>

// Antecedents: ant[i, r] = prod_j m_j[i, ri[r][j]], N=16384, n_sets=5x5x5x5x5,
// R = 3125, r = a*625 + b*125 + c*25 + d*5 + e (meshgrid 'ij' order).
// Pure streaming-write kernel: 204.8 MB out, 1.6 MB in.

#define NSAMP 16384
#define NRULE 3125

__global__ __launch_bounds__(256) void antecedents_kernel(
    const float* __restrict__ m0, const float* __restrict__ m1,
    const float* __restrict__ m2, const float* __restrict__ m3,
    const float* __restrict__ m4, float* __restrict__ out)
{
    __shared__ float p012[125];  // m0[a]*m1[b]*m2[c], index a*25+b*5+c
    __shared__ float p34[25];    // m3[d]*m4[e],       index d*5+e

    const int i = blockIdx.x;          // sample row
    const unsigned t = threadIdx.x;

    // Stage partial products into LDS. Inputs are tiny (1.6 MB total) and
    // L2-resident after the first few blocks; redundant global reads are cheap.
    if (t < 125u) {
        const unsigned a = t / 25u;
        const unsigned b = (t / 5u) % 5u;
        const unsigned c = t % 5u;
        p012[t] = m0[i * 5 + a] * m1[i * 5 + b] * m2[i * 5 + c];
    } else if (t < 150u) {
        const unsigned u = t - 125u;
        const unsigned d = u / 5u;
        const unsigned e = u % 5u;
        p34[u] = m3[i * 5 + d] * m4[i * 5 + e];
    }
    __syncthreads();

    float* __restrict__ orow = out + (size_t)i * NRULE;
    // 3125 / 256 -> ~12.2 coalesced dword stores per thread.
    for (unsigned r = t; r < NRULE; r += 256u) {
        const unsigned hi = r / 25u;        // a*25+b*5+c  (magic-mul)
        const unsigned lo = r - hi * 25u;   // d*5+e
        orow[r] = p012[hi] * p34[lo];
    }
}

extern "C" void kernel_launch(void* const* d_in, const int* in_sizes, int n_in,
                              void* d_out, int out_size, void* d_ws, size_t ws_size,
                              hipStream_t stream) {
    const float* m0 = (const float*)d_in[0];
    const float* m1 = (const float*)d_in[1];
    const float* m2 = (const float*)d_in[2];
    const float* m3 = (const float*)d_in[3];
    const float* m4 = (const float*)d_in[4];
    float* out = (float*)d_out;

    antecedents_kernel<<<NSAMP, 256, 0, stream>>>(m0, m1, m2, m3, m4, out);
}